// Round 5
// baseline (503.297 us; speedup 1.0000x reference)
//
#include <hip/hip_runtime.h>
#include <hip/hip_bf16.h>
#include <math.h>

#define NT 128
#define NB 16
#define TT 8
#define C 512
#define RR 64
#define HW 784
#define HH 28
#define WW 28
#define PP 3
#define NN 24
#define EPS 1e-5f

typedef __attribute__((ext_vector_type(8))) short bh8;
typedef __attribute__((ext_vector_type(4))) float f32x4;
typedef unsigned short u16;
typedef unsigned int u32;

static __device__ inline u16 f2bf(float f) {
    __hip_bfloat16 h = __float2bfloat16(f);
    return *(u16*)&h;
}
static __device__ inline float bf2f(u16 u) {
    __hip_bfloat16 h;
    *(u16*)&h = u;
    return __bfloat162float(h);
}
static __device__ inline void pack8(const float* x, u32* hp, u32* lp) {
    #pragma unroll
    for (int i = 0; i < 4; ++i) {
        u16 h0 = f2bf(x[2 * i]), h1 = f2bf(x[2 * i + 1]);
        u16 l0 = f2bf(x[2 * i] - bf2f(h0));
        u16 l1 = f2bf(x[2 * i + 1] - bf2f(h1));
        hp[i] = (u32)h0 | ((u32)h1 << 16);
        lp[i] = (u32)l0 | ((u32)l1 << 16);
    }
}

// ---------------- Kernel A (MFMA): conv1 (1x1x1, C->64) + BN + LReLU ----------------
// Tile 128hw x 64r, K=512. LDS X stored [hw][k] (k-contiguous) so B-fragment
// is ONE ds_read_b128 per lane. 16B-slot XOR swizzle for banks.
// Output s1p: u32 = bf16_hi | bf16_lo<<16 per element.
__global__ __launch_bounds__(256) void convA_mfma(const float* __restrict__ X,
        const float* __restrict__ W1, const float* __restrict__ cb,
        const float* __restrict__ g, const float* __restrict__ bb,
        const float* __restrict__ m, const float* __restrict__ v,
        u32* __restrict__ s1p)
{
    __shared__ u16 Xh[128 * 32];   // [hw][k], 64B rows, swizzled 16B slots
    __shared__ u16 Xl[128 * 32];
    __shared__ u16 Wh[4 * 64 * 8]; // [rt][lane][8k] pre-packed fragments
    __shared__ u16 Wl[4 * 64 * 8];
    __shared__ float sInv[64], sAdd[64], sCb[64];

    const int nt  = blockIdx.y;
    const int hw0 = blockIdx.x * 128;
    const int tid = threadIdx.x;

    if (tid < 64) {
        float inv = g[tid] * rsqrtf(v[tid] + EPS);
        sInv[tid] = inv;
        sAdd[tid] = bb[tid] - m[tid] * inv;
        sCb[tid]  = cb[tid];
    }

    // staging roles: thread owns one hw column, 16 k's
    const int hwl = tid & 127;
    const int kg  = tid >> 7;          // 0..1
    const int hw_g = hw0 + hwl;
    const bool hok = hw_g < HW;
    // W staging roles
    const int wr = tid >> 2, wj = tid & 3;
    // compute roles: wave quadrant 32r x 64hw
    const int w  = tid >> 6, l = tid & 63;
    const int rh = w >> 1, hh = w & 1;
    const int gq = l >> 4, mm = l & 15;
    const int rslot = gq ^ (mm & 3) ^ ((mm >> 2) & 3);

    f32x4 acc[2][4];
    #pragma unroll
    for (int i = 0; i < 2; ++i)
        #pragma unroll
        for (int jj = 0; jj < 4; ++jj) acc[i][jj] = (f32x4){0.f, 0.f, 0.f, 0.f};

    const float* Xnt = X + (size_t)nt * C * HW;

    for (int k0 = 0; k0 < C; k0 += 32) {
        // global loads (issue early)
        float xv[16];
        #pragma unroll
        for (int j = 0; j < 16; ++j)
            xv[j] = hok ? Xnt[(size_t)(k0 + kg * 16 + j) * HW + hw_g] : 0.f;
        const float* wsrc = W1 + (size_t)wr * C + k0 + wj * 8;
        float4 wa = *(const float4*)wsrc;
        float4 wb = *(const float4*)(wsrc + 4);

        __syncthreads();   // prior compute reads done
        // X writes: [hw][k] with swizzled 16B slots
        #pragma unroll
        for (int q = 0; q < 2; ++q) {
            u32 hp[4], lp[4];
            pack8(&xv[q * 8], hp, lp);
            int slot = ((kg << 1) | q) ^ (hwl & 3) ^ ((hwl >> 2) & 3);
            *(uint4*)&Xh[hwl * 32 + slot * 8] = make_uint4(hp[0], hp[1], hp[2], hp[3]);
            *(uint4*)&Xl[hwl * 32 + slot * 8] = make_uint4(lp[0], lp[1], lp[2], lp[3]);
        }
        // W writes: fragment order
        {
            float x[8] = {wa.x, wa.y, wa.z, wa.w, wb.x, wb.y, wb.z, wb.w};
            u32 hp[4], lp[4];
            pack8(x, hp, lp);
            int woff = ((wr >> 4) * 64 + (wr & 15) + 16 * wj) * 8;
            *(uint4*)&Wh[woff] = make_uint4(hp[0], hp[1], hp[2], hp[3]);
            *(uint4*)&Wl[woff] = make_uint4(lp[0], lp[1], lp[2], lp[3]);
        }
        __syncthreads();

        // B fragments: one b128 each
        bh8 fxh[4], fxl[4];
        #pragma unroll
        for (int nb = 0; nb < 4; ++nb) {
            int hwrow = (hh << 6) + (nb << 4) + mm;
            fxh[nb] = *(const bh8*)&Xh[hwrow * 32 + rslot * 8];
            fxl[nb] = *(const bh8*)&Xl[hwrow * 32 + rslot * 8];
        }
        #pragma unroll
        for (int rr = 0; rr < 2; ++rr) {
            int rt = (rh << 1) | rr;
            bh8 wh = *(const bh8*)&Wh[(rt * 64 + l) * 8];
            bh8 wl = *(const bh8*)&Wl[(rt * 64 + l) * 8];
            #pragma unroll
            for (int nb = 0; nb < 4; ++nb) {
                acc[rr][nb] = __builtin_amdgcn_mfma_f32_16x16x32_bf16(wh, fxh[nb], acc[rr][nb], 0, 0, 0);
                acc[rr][nb] = __builtin_amdgcn_mfma_f32_16x16x32_bf16(wh, fxl[nb], acc[rr][nb], 0, 0, 0);
                acc[rr][nb] = __builtin_amdgcn_mfma_f32_16x16x32_bf16(wl, fxh[nb], acc[rr][nb], 0, 0, 0);
            }
        }
    }

    // epilogue: BN + LReLU, store packed hi/lo
    #pragma unroll
    for (int rr = 0; rr < 2; ++rr) {
        #pragma unroll
        for (int nb = 0; nb < 4; ++nb) {
            int hw = hw0 + (hh << 6) + (nb << 4) + mm;
            if (hw < HW) {
                #pragma unroll
                for (int reg = 0; reg < 4; ++reg) {
                    int r = (((rh << 1) | rr) << 4) + (gq << 2) + reg;
                    float y = (acc[rr][nb][reg] + sCb[r]) * sInv[r] + sAdd[r];
                    y = (y >= 0.f) ? y : 0.05f * y;
                    u16 h = f2bf(y);
                    u16 lo = f2bf(y - bf2f(h));
                    s1p[((size_t)nt * RR + r) * HW + hw] = (u32)h | ((u32)lo << 16);
                }
            }
        }
    }
}

// ---------------- Kernel B (MFMA): conv2 (3x1x1 over t, 64->64) + bias ----------------
// Same tile machinery; input already packed bf16 hi/lo. W2 packed per-dt.
__global__ __launch_bounds__(256) void convB_mfma(const u32* __restrict__ s1p,
        const float* __restrict__ W2, const float* __restrict__ cb,
        float* __restrict__ s2)
{
    __shared__ u16 Xh[128 * 32];
    __shared__ u16 Xl[128 * 32];
    __shared__ u16 Wh[2 * 2048];   // [kc][rt][lane][8]
    __shared__ u16 Wl[2 * 2048];

    const int nt  = blockIdx.y;
    const int n = nt >> 3, t = nt & 7;
    const int hw0 = blockIdx.x * 128;
    const int tid = threadIdx.x;

    const int hwl = tid & 127;
    const int kg  = tid >> 7;
    const int hw_g = hw0 + hwl;
    const bool hok = hw_g < HW;
    const int wr = tid >> 2, wj = tid & 3;
    const int w  = tid >> 6, l = tid & 63;
    const int rh = w >> 1, hh = w & 1;
    const int gq = l >> 4, mm = l & 15;
    const int rslot = gq ^ (mm & 3) ^ ((mm >> 2) & 3);

    f32x4 acc[2][4];
    #pragma unroll
    for (int i = 0; i < 2; ++i)
        #pragma unroll
        for (int jj = 0; jj < 4; ++jj) acc[i][jj] = (f32x4){0.f, 0.f, 0.f, 0.f};

    for (int dt = 0; dt < 3; ++dt) {
        int tp = t + dt - 1;
        if (tp < 0 || tp >= TT) continue;   // block-uniform
        __syncthreads();                    // prior reads of Wh/Xh done
        // pack W for this dt (2 kc chunks)
        #pragma unroll
        for (int kc = 0; kc < 2; ++kc) {
            const float* wsrc = W2 + (size_t)wr * 192 + (kc * 32 + wj * 8) * 3 + dt;
            float x[8];
            #pragma unroll
            for (int i = 0; i < 8; ++i) x[i] = wsrc[i * 3];
            u32 hp[4], lp[4];
            pack8(x, hp, lp);
            int woff = kc * 2048 + ((wr >> 4) * 64 + (wr & 15) + 16 * wj) * 8;
            *(uint4*)&Wh[woff] = make_uint4(hp[0], hp[1], hp[2], hp[3]);
            *(uint4*)&Wl[woff] = make_uint4(lp[0], lp[1], lp[2], lp[3]);
        }
        const size_t pbase = (size_t)(n * TT + tp) * RR * HW;
        #pragma unroll
        for (int kc = 0; kc < 2; ++kc) {
            u32 xv[16];
            #pragma unroll
            for (int j = 0; j < 16; ++j)
                xv[j] = hok ? s1p[pbase + (size_t)(kc * 32 + kg * 16 + j) * HW + hw_g] : 0u;
            __syncthreads();   // prior compute reads done (and W-pack visible before next barrier)
            #pragma unroll
            for (int q = 0; q < 2; ++q) {
                u32 hp[4], lp[4];
                #pragma unroll
                for (int i = 0; i < 4; ++i) {
                    u32 u0 = xv[q * 8 + 2 * i], u1 = xv[q * 8 + 2 * i + 1];
                    hp[i] = (u0 & 0xffffu) | (u1 << 16);
                    lp[i] = (u0 >> 16) | (u1 & 0xffff0000u);
                }
                int slot = ((kg << 1) | q) ^ (hwl & 3) ^ ((hwl >> 2) & 3);
                *(uint4*)&Xh[hwl * 32 + slot * 8] = make_uint4(hp[0], hp[1], hp[2], hp[3]);
                *(uint4*)&Xl[hwl * 32 + slot * 8] = make_uint4(lp[0], lp[1], lp[2], lp[3]);
            }
            __syncthreads();

            bh8 fxh[4], fxl[4];
            #pragma unroll
            for (int nb = 0; nb < 4; ++nb) {
                int hwrow = (hh << 6) + (nb << 4) + mm;
                fxh[nb] = *(const bh8*)&Xh[hwrow * 32 + rslot * 8];
                fxl[nb] = *(const bh8*)&Xl[hwrow * 32 + rslot * 8];
            }
            #pragma unroll
            for (int rr = 0; rr < 2; ++rr) {
                int rt = (rh << 1) | rr;
                bh8 wh = *(const bh8*)&Wh[kc * 2048 + (rt * 64 + l) * 8];
                bh8 wl = *(const bh8*)&Wl[kc * 2048 + (rt * 64 + l) * 8];
                #pragma unroll
                for (int nb = 0; nb < 4; ++nb) {
                    acc[rr][nb] = __builtin_amdgcn_mfma_f32_16x16x32_bf16(wh, fxh[nb], acc[rr][nb], 0, 0, 0);
                    acc[rr][nb] = __builtin_amdgcn_mfma_f32_16x16x32_bf16(wh, fxl[nb], acc[rr][nb], 0, 0, 0);
                    acc[rr][nb] = __builtin_amdgcn_mfma_f32_16x16x32_bf16(wl, fxh[nb], acc[rr][nb], 0, 0, 0);
                }
            }
        }
    }

    #pragma unroll
    for (int rr = 0; rr < 2; ++rr) {
        #pragma unroll
        for (int nb = 0; nb < 4; ++nb) {
            int hw = hw0 + (hh << 6) + (nb << 4) + mm;
            if (hw < HW) {
                #pragma unroll
                for (int reg = 0; reg < 4; ++reg) {
                    int r = (((rh << 1) | rr) << 4) + (gq << 2) + reg;
                    s2[((size_t)nt * RR + r) * HW + hw] = acc[rr][nb][reg] + cb[r];
                }
            }
        }
    }
}

// ---------------- Kernel C: conv3 (1x5x5, 64->3, pad 2), sliding window ----------------
__global__ __launch_bounds__(256) void convC_sw(const float* __restrict__ s2,
        const float* __restrict__ W3, float* __restrict__ partial)
{
    const int tid  = threadIdx.x;
    const int wave = tid >> 6;
    const int lane = tid & 63;
    const int half = lane >> 5;
    const int col  = lane & 31;
    const int item = blockIdx.x * 8 + wave * 2 + half;
    const int band = item & 3;
    const int nt   = (item >> 2) & 127;
    int cg = item >> 9;
    cg = __builtin_amdgcn_readfirstlane(cg);

    const int row0 = band * 7;
    const bool cok = (col < 28);

    float acc[3][7];
    #pragma unroll
    for (int p = 0; p < 3; ++p)
        #pragma unroll
        for (int r = 0; r < 7; ++r) acc[p][r] = 0.f;

    for (int chi = 0; chi < 8; ++chi) {
        float wgt[75];
        #pragma unroll
        for (int p = 0; p < 3; ++p)
            #pragma unroll
            for (int q = 0; q < 25; ++q)
                wgt[p * 25 + q] = W3[(size_t)(p * 64 + cg * 8 + chi) * 25 + q];

        const float* src = s2 + ((size_t)nt * RR + cg * 8 + chi) * HW;
        float wdw[5][5];

        #pragma unroll
        for (int rr = 0; rr < 4; ++rr) {
            int R = row0 - 2 + rr;
            bool rok = (R >= 0) & (R < HH);
            #pragma unroll
            for (int j = 0; j < 5; ++j) {
                int cc = col - 2 + j;
                bool ok = rok & cok & (cc >= 0) & (cc < WW);
                wdw[rr][j] = ok ? src[R * WW + cc] : 0.f;
            }
        }
        #pragma unroll
        for (int r = 0; r < 7; ++r) {
            {
                int R = row0 + 2 + r;
                bool rok = (R < HH);
                int slot = (r + 4) % 5;
                #pragma unroll
                for (int j = 0; j < 5; ++j) {
                    int cc = col - 2 + j;
                    bool ok = rok & cok & (cc >= 0) & (cc < WW);
                    wdw[slot][j] = ok ? src[R * WW + cc] : 0.f;
                }
            }
            #pragma unroll
            for (int p = 0; p < 3; ++p)
                #pragma unroll
                for (int dh = 0; dh < 5; ++dh)
                    #pragma unroll
                    for (int dw = 0; dw < 5; ++dw)
                        acc[p][r] += wdw[(r + dh) % 5][dw] * wgt[p * 25 + dh * 5 + dw];
        }
    }

    if (cok) {
        #pragma unroll
        for (int p = 0; p < 3; ++p)
            #pragma unroll
            for (int r = 0; r < 7; ++r)
                partial[(((size_t)cg * 128 + nt) * 3 + p) * HW + (row0 + r) * WW + col]
                    = acc[p][r];
    }
}

// ---------------- Kernel C2: reduce partials + bias + BN + sigmoid ----------------
__global__ __launch_bounds__(256) void convC_fin(const float* __restrict__ partial,
        const float* __restrict__ cb, const float* __restrict__ g,
        const float* __restrict__ bb, const float* __restrict__ m,
        const float* __restrict__ v, float* __restrict__ smap)
{
    const int idx = blockIdx.x * 256 + threadIdx.x;
    const int total = 128 * 3 * HW;
    if (idx >= total) return;
    const int p = (idx / HW) % 3;
    float a = cb[p];
    #pragma unroll
    for (int gg = 0; gg < 8; ++gg) a += partial[(size_t)gg * total + idx];
    float inv = g[p] * rsqrtf(v[p] + EPS);
    float z = a * inv + (bb[p] - m[p] * inv);
    smap[idx] = 1.f / (1.f + expf(-z));
}

// ---------------- Kernel D: weighted node pooling + residual mean ----------------
__global__ __launch_bounds__(256) void poolD(const float* __restrict__ X,
        const float* __restrict__ smap, float* __restrict__ nodes,
        float* __restrict__ out)
{
    const int tid = threadIdx.x;
    const int lane = tid & 63;
    const int gw = blockIdx.x * 4 + (tid >> 6);
    const int c = gw & 511;
    const int nt = gw >> 9;
    const float4* X4 = (const float4*)(X + ((size_t)nt * C + c) * HW);
    const float4* S0 = (const float4*)(smap + (size_t)nt * PP * HW);
    const float4* S1 = S0 + 196;
    const float4* S2 = S1 + 196;
    float sx = 0.f, a0 = 0.f, a1 = 0.f, a2 = 0.f;
    #pragma unroll
    for (int i = 0; i < 4; ++i) {
        int fi = i * 64 + lane;
        if (fi < 196) {
            float4 x = X4[fi];
            float4 p0 = S0[fi], p1 = S1[fi], p2 = S2[fi];
            sx += x.x + x.y + x.z + x.w;
            a0 += x.x * p0.x + x.y * p0.y + x.z * p0.z + x.w * p0.w;
            a1 += x.x * p1.x + x.y * p1.y + x.z * p1.z + x.w * p1.w;
            a2 += x.x * p2.x + x.y * p2.y + x.z * p2.z + x.w * p2.w;
        }
    }
    #pragma unroll
    for (int off = 32; off >= 1; off >>= 1) {
        sx += __shfl_xor(sx, off);
        a0 += __shfl_xor(a0, off);
        a1 += __shfl_xor(a1, off);
        a2 += __shfl_xor(a2, off);
    }
    if (lane == 0) {
        int n = nt >> 3, t = nt & 7;
        const float s = 1.f / 784.f;
        out[((size_t)n * 9 + 1 + t) * C + c] = sx * s;
        float* nd = nodes + ((size_t)n * NN + t * PP) * C + c;
        nd[0]     = a0 * s;
        nd[C]     = a1 * s;
        nd[2 * C] = a2 * s;
    }
}

// ---------------- Kernel E1: normalized Laplacian ----------------
__global__ __launch_bounds__(256) void graphL(const float* __restrict__ nodes,
        float* __restrict__ Lg)
{
    __shared__ float4 nds[24][129];
    __shared__ float Amat[24][24];
    __shared__ float dinv[24];
    const int n = blockIdx.x;
    const int tid = threadIdx.x;
    const float4* src = (const float4*)(nodes + (size_t)n * NN * C);
    #pragma unroll
    for (int i = 0; i < 12; ++i) {
        int fi = tid + i * 256;
        int row = fi >> 7, k4 = fi & 127;
        nds[row][k4] = src[row * 128 + k4];
    }
    __syncthreads();
    for (int pair = tid; pair < 576; pair += 256) {
        int i = pair / 24, j = pair - (pair / 24) * 24;
        const float4* ri = &nds[i][0];
        const float4* rj = &nds[j][0];
        float s = 0.f;
        for (int k = 0; k < 128; ++k) {
            float4 a = ri[k], b = rj[k];
            s += a.x * b.x + a.y * b.y + a.z * b.z + a.w * b.w;
        }
        Amat[i][j] = s * (1.f / 512.f);
    }
    __syncthreads();
    if (tid < 24) {
        float d = 0.f;
        for (int j = 0; j < 24; ++j) d += Amat[tid][j];
        d = fmaxf(d, 1e-8f);
        dinv[tid] = 1.f / sqrtf(d);
    }
    __syncthreads();
    for (int pair = tid; pair < 576; pair += 256) {
        int i = pair / 24, j = pair - (pair / 24) * 24;
        Lg[(size_t)n * 576 + pair] = dinv[i] * Amat[i][j] * dinv[j];
    }
}

// ---------------- Kernel G: Y[384,512] = Xin[384,512] @ W^T ----------------
__global__ __launch_bounds__(256) void gemmG(const float* __restrict__ Xin,
        const float* __restrict__ Wm, float* __restrict__ Y)
{
    __shared__ float Xs[32][36];
    __shared__ float Ws[32][66];
    const int o0 = blockIdx.x * 64;
    const int m0 = blockIdx.y * 32;
    const int tid = threadIdx.x;
    const int tr = tid >> 5;
    const int tc = tid & 31;
    float acc[4][2] = {};

    for (int k0 = 0; k0 < 512; k0 += 32) {
        {
            int ml = tid >> 3, k4 = tid & 7;
            float4 xv = *(const float4*)&Xin[(size_t)(m0 + ml) * 512 + k0 + k4 * 4];
            Xs[k4 * 4 + 0][ml] = xv.x; Xs[k4 * 4 + 1][ml] = xv.y;
            Xs[k4 * 4 + 2][ml] = xv.z; Xs[k4 * 4 + 3][ml] = xv.w;
        }
        #pragma unroll
        for (int i = 0; i < 2; ++i) {
            int idx = tid + i * 256;
            int ol = idx >> 3, k4 = idx & 7;
            float4 wv = *(const float4*)&Wm[(size_t)(o0 + ol) * 512 + k0 + k4 * 4];
            Ws[k4 * 4 + 0][ol] = wv.x; Ws[k4 * 4 + 1][ol] = wv.y;
            Ws[k4 * 4 + 2][ol] = wv.z; Ws[k4 * 4 + 3][ol] = wv.w;
        }
        __syncthreads();
        #pragma unroll
        for (int k = 0; k < 32; ++k) {
            float4 xv = *(const float4*)&Xs[k][tr * 4];
            float2 wv = *(const float2*)&Ws[k][tc * 2];
            acc[0][0] += xv.x * wv.x; acc[0][1] += xv.x * wv.y;
            acc[1][0] += xv.y * wv.x; acc[1][1] += xv.y * wv.y;
            acc[2][0] += xv.z * wv.x; acc[2][1] += xv.z * wv.y;
            acc[3][0] += xv.w * wv.x; acc[3][1] += xv.w * wv.y;
        }
        __syncthreads();
    }
    #pragma unroll
    for (int i2 = 0; i2 < 4; ++i2)
        #pragma unroll
        for (int j = 0; j < 2; ++j)
            Y[(size_t)(m0 + tr * 4 + i2) * 512 + o0 + tc * 2 + j] = acc[i2][j];
}

// ---------------- Kernel LX: Xg = lrelu(L @ G) per n ----------------
__global__ __launch_bounds__(256) void applyL(const float* __restrict__ G,
        const float* __restrict__ Lg, float* __restrict__ Xg)
{
    __shared__ float Ls[576];
    const int n = blockIdx.y;
    const int tid = threadIdx.x;
    for (int i = tid; i < 576; i += 256) Ls[i] = Lg[(size_t)n * 576 + i];
    __syncthreads();
    const int o = blockIdx.x * 128 + (tid & 127);
    const int ig = (tid >> 7) * 12;
    float acc[12] = {};
    const float* Gn = G + (size_t)n * NN * 512;
    for (int j = 0; j < 24; ++j) {
        float gv = Gn[j * 512 + o];
        #pragma unroll
        for (int i = 0; i < 12; ++i)
            acc[i] += Ls[(ig + i) * 24 + j] * gv;
    }
    float* Xn = Xg + (size_t)n * NN * 512;
    #pragma unroll
    for (int i = 0; i < 12; ++i) {
        float y = acc[i];
        Xn[(ig + i) * 512 + o] = (y >= 0.f) ? y : 0.05f * y;
    }
}

// ---------------- Kernel E4: attention readout -> out row 0 ----------------
__global__ __launch_bounds__(256) void attE(const float* __restrict__ Xg,
        const float* __restrict__ nodes, const float* __restrict__ Lg,
        const float* __restrict__ aw, const float* __restrict__ ab,
        float* __restrict__ out)
{
    __shared__ float zs[24], ys[24], att[24], Ls[576];
    const int n = blockIdx.x;
    const int tid = threadIdx.x;
    const int lane = tid & 63, wv = tid >> 6;
    for (int i = tid; i < 576; i += 256) Ls[i] = Lg[(size_t)n * 576 + i];
    const float* Xn = Xg + (size_t)n * NN * 512;
    const float* Nn = nodes + (size_t)n * NN * 512;
    for (int i = wv; i < 24; i += 4) {
        float s = 0.f;
        #pragma unroll
        for (int kk = 0; kk < 8; ++kk) {
            int k = kk * 64 + lane;
            s += (Xn[i * 512 + k] + Nn[i * 512 + k]) * aw[k];
        }
        #pragma unroll
        for (int off = 32; off >= 1; off >>= 1) s += __shfl_xor(s, off);
        if (lane == 0) zs[i] = s;
    }
    __syncthreads();
    if (tid < 24) {
        float y = ab[0];
        for (int j = 0; j < 24; ++j) y += Ls[tid * 24 + j] * zs[j];
        ys[tid] = y;
    }
    __syncthreads();
    if (tid < 64) {
        float vv = (tid < 24) ? ys[tid] : -3.4e38f;
        float mx = vv;
        #pragma unroll
        for (int off = 32; off >= 1; off >>= 1) mx = fmaxf(mx, __shfl_xor(mx, off));
        float e = (tid < 24) ? expf(vv - mx) : 0.f;
        float ssum = e;
        #pragma unroll
        for (int off = 32; off >= 1; off >>= 1) ssum += __shfl_xor(ssum, off);
        if (tid < 24) att[tid] = e / ssum;
    }
    __syncthreads();
    for (int c2 = tid; c2 < 512; c2 += 256) {
        float r = 0.f;
        #pragma unroll
        for (int i = 0; i < 24; ++i) r += Xn[i * 512 + c2] * att[i];
        out[(size_t)n * 9 * 512 + c2] = r;
    }
}

extern "C" void kernel_launch(void* const* d_in, const int* in_sizes, int n_in,
                              void* d_out, int out_size, void* d_ws, size_t ws_size,
                              hipStream_t stream)
{
    const float* X   = (const float*)d_in[0];
    const float* w1  = (const float*)d_in[1];
    const float* b1c = (const float*)d_in[2];
    const float* g1  = (const float*)d_in[3];
    const float* b1  = (const float*)d_in[4];
    const float* m1  = (const float*)d_in[5];
    const float* v1  = (const float*)d_in[6];
    const float* w2  = (const float*)d_in[7];
    const float* b2c = (const float*)d_in[8];
    const float* w3  = (const float*)d_in[9];
    const float* b3c = (const float*)d_in[10];
    const float* g2  = (const float*)d_in[11];
    const float* b2  = (const float*)d_in[12];
    const float* m2  = (const float*)d_in[13];
    const float* v2  = (const float*)d_in[14];
    const float* gw0 = (const float*)d_in[15];
    const float* gw1 = (const float*)d_in[16];
    const float* aw  = (const float*)d_in[17];
    const float* ab  = (const float*)d_in[18];
    float* out = (float*)d_out;

    const size_t S1N = (size_t)NT * RR * HW;   // 6422528
    u32*   s1p   = (u32*)d_ws;
    float* part  = (float*)d_ws;               // overlays s1p (dead after convB)
    float* s2    = (float*)(s1p + S1N);
    float* smap  = s2 + S1N;
    float* nodes = smap + (size_t)NT * PP * HW;
    float* Lg    = nodes + (size_t)NB * NN * C;
    float* gt    = Lg + (size_t)NB * NN * NN;
    float* xa    = gt + (size_t)NB * NN * C;
    float* xb    = xa + (size_t)NB * NN * C;

    convA_mfma<<<dim3(7, NT), 256, 0, stream>>>(X, w1, b1c, g1, b1, m1, v1, s1p);
    convB_mfma<<<dim3(7, NT), 256, 0, stream>>>(s1p, w2, b2c, s2);
    convC_sw<<<dim3(512), 256, 0, stream>>>(s2, w3, part);
    convC_fin<<<dim3(1176), 256, 0, stream>>>(part, b3c, g2, b2, m2, v2, smap);
    poolD<<<dim3(16384), 256, 0, stream>>>(X, smap, nodes, out);
    graphL<<<dim3(NB), 256, 0, stream>>>(nodes, Lg);
    gemmG<<<dim3(8, 12), 256, 0, stream>>>(nodes, gw0, gt);
    applyL<<<dim3(4, NB), 256, 0, stream>>>(gt, Lg, xa);
    gemmG<<<dim3(8, 12), 256, 0, stream>>>(xa, gw1, gt);
    applyL<<<dim3(4, NB), 256, 0, stream>>>(gt, Lg, xb);
    attE<<<dim3(NB), 256, 0, stream>>>(xb, nodes, Lg, aw, ab, out);
}